// Round 6
// baseline (311.434 us; speedup 1.0000x reference)
//
#include <hip/hip_runtime.h>

#define NCLS 13
#define DIM  256
#define INV_T (1.0f/0.07f)

typedef short bf16x8 __attribute__((ext_vector_type(8)));
typedef float f32x4  __attribute__((ext_vector_type(4)));

__device__ __forceinline__ float bf2f(unsigned short u){
  union { unsigned u; float f; } v; v.u = ((unsigned)u) << 16; return v.f;
}
__device__ __forceinline__ unsigned short f2bf(float f){
  union { float f; unsigned u; } v; v.f = f;
  unsigned r = v.u + 0x7fffu + ((v.u >> 16) & 1u);
  return (unsigned short)(r >> 16);
}

// ---------------- prep kernels ----------------

__global__ void k_zero(int* counts, double* accum, int n){
  int i = blockIdx.x*blockDim.x + threadIdx.x;
  if (i < n) counts[i] = 0;
  if (i == 0) *accum = 0.0;
}

__global__ void k_hist(const int* __restrict__ idx, const int* __restrict__ lab,
                       int* __restrict__ counts, int n){
  int i = blockIdx.x*blockDim.x + threadIdx.x;
  if (i < n) atomicAdd(&counts[idx[i]*NCLS + lab[i]], 1);
}

// one block, M threads (M=1024). argmax labels + deterministic label-sorted permutation.
__global__ void k_label_perm(const int* __restrict__ counts, int* __restrict__ spLabel,
                             int* __restrict__ newpos, int* __restrict__ permLabel){
  int m = threadIdx.x;
  int best = 0; int bc = counts[m*NCLS];
  #pragma unroll
  for (int c = 1; c < NCLS; ++c){ int v = counts[m*NCLS+c]; if (v > bc){ bc = v; best = c; } }
  spLabel[m] = best;

  __shared__ int waveCnt[16][NCLS];
  __shared__ int waveOff[16][NCLS];
  __shared__ int classTot[NCLS];
  __shared__ int classBase[NCLS];
  int lane = m & 63, wid = m >> 6;
  int nw = blockDim.x >> 6;
  int rankInWave = 0;
  unsigned long long below = (1ull << lane) - 1ull;
  for (int c = 0; c < NCLS; ++c){
    unsigned long long bal = __ballot(best == c);
    if (best == c) rankInWave = __popcll(bal & below);
    if (lane == 0) waveCnt[wid][c] = __popcll(bal);
  }
  __syncthreads();
  if (m < NCLS){
    int c = m, s = 0;
    for (int w = 0; w < nw; ++w){ waveOff[w][c] = s; s += waveCnt[w][c]; }
    classTot[c] = s;
  }
  __syncthreads();
  if (m == 0){ int s = 0; for (int c = 0; c < NCLS; ++c){ classBase[c] = s; s += classTot[c]; } }
  __syncthreads();
  int pos = classBase[best] + waveOff[wid][best] + rankInWave;
  newpos[m] = pos;
  permLabel[pos] = best;
}

// one wave per superpoint row: normalize, write bf16 in original and permuted order
__global__ void k_norm_sp(const float* __restrict__ sp, const int* __restrict__ newpos,
                          unsigned short* __restrict__ spnO, unsigned short* __restrict__ spnP){
  int m = blockIdx.x, lane = threadIdx.x;
  const float4 v = *(const float4*)(sp + (size_t)m*DIM + lane*4);
  float ss = v.x*v.x + v.y*v.y + v.z*v.z + v.w*v.w;
  #pragma unroll
  for (int o = 1; o < 64; o <<= 1) ss += __shfl_xor(ss, o);
  float rn = 1.0f / sqrtf(ss + 1e-12f);
  uint2 w;
  w.x = (unsigned)f2bf(v.x*rn) | ((unsigned)f2bf(v.y*rn) << 16);
  w.y = (unsigned)f2bf(v.z*rn) | ((unsigned)f2bf(v.w*rn) << 16);
  *(uint2*)(spnO + (size_t)m*DIM + lane*4) = w;
  int p = newpos[m];
  *(uint2*)(spnP + (size_t)p*DIM + lane*4) = w;
}

// ---------------- main fused GEMM (barrier-free K loop) ----------------
// BM=128 rows/block, 256 threads = 4 waves in 2x2 grid; wave tile 64r x 64c.
// A: 128x256 bf16 in swizzled LDS, staged once (fused normalize), ONE barrier.
// B: read per-fragment from global (spnP is 512 KB -> L2-resident, reused by
//    every block). No B staging, no in-loop __syncthreads.
// LDS = 64K(A) + ~2K = 66 KB -> 2 blocks/CU = 2 waves/EU.
// waves_per_eu(1,2): min 1 -> register budget unclamped (the 64/128-reg
// clamps in earlier rounds каused 78/43 MB scratch spills); max 2 matches
// the LDS-implied occupancy.

__device__ __forceinline__ int swzA(int row, int k){ return (row*DIM + k) ^ ((row & 7) << 3); }

__attribute__((amdgpu_waves_per_eu(1, 2)))
__launch_bounds__(256)
__global__ void k_main(const float* __restrict__ rp, const int* __restrict__ rawIdx,
                       const unsigned short* __restrict__ spnO, const unsigned short* __restrict__ spnP,
                       const int* __restrict__ permLabel, const int* __restrict__ spLabel,
                       double* __restrict__ accum, int M){
  __shared__ __align__(16) unsigned short Ash[128*DIM];   // 64 KB
  __shared__ float posLogit[128];
  __shared__ int   posLab[128];
  __shared__ float negH[2][128];

  const int tid  = threadIdx.x;
  const int lane = tid & 63, wid = tid >> 6;
  const int l15  = lane & 15, l4 = lane >> 4;
  const int rowBlock = blockIdx.x * 128;

  // stage A: normalize 128 rp rows -> bf16 LDS (one wave per 32 rows)
  for (int rr = 0; rr < 32; ++rr){
    int row = wid*32 + rr;
    const float4 v = *(const float4*)(rp + (size_t)(rowBlock + row)*DIM + lane*4);
    float ss = v.x*v.x + v.y*v.y + v.z*v.z + v.w*v.w;
    #pragma unroll
    for (int o = 1; o < 64; o <<= 1) ss += __shfl_xor(ss, o);
    float rn = 1.0f / sqrtf(ss + 1e-12f);
    uint2 w;
    w.x = (unsigned)f2bf(v.x*rn) | ((unsigned)f2bf(v.y*rn) << 16);
    w.y = (unsigned)f2bf(v.z*rn) | ((unsigned)f2bf(v.w*rn) << 16);
    *(uint2*)&Ash[swzA(row, lane*4)] = w;
  }

  // positive logits (rows staged by this same wave: no barrier needed yet)
  for (int rr = 0; rr < 32; ++rr){
    int row  = wid*32 + rr;
    int sidx = rawIdx[rowBlock + row];
    uint2 av = *(const uint2*)&Ash[swzA(row, lane*4)];
    uint2 sv = *(const uint2*)(spnO + (size_t)sidx*DIM + lane*4);
    float d = bf2f(av.x & 0xffff)*bf2f(sv.x & 0xffff)
            + bf2f(av.x >> 16)  *bf2f(sv.x >> 16)
            + bf2f(av.y & 0xffff)*bf2f(sv.y & 0xffff)
            + bf2f(av.y >> 16)  *bf2f(sv.y >> 16);
    #pragma unroll
    for (int o = 1; o < 64; o <<= 1) d += __shfl_xor(d, o);
    if (lane == 0){ posLogit[row] = d; posLab[row] = spLabel[sidx]; }
  }
  __syncthreads();   // the ONLY barrier before the end

  const int wr = wid >> 1, wc = wid & 1;
  float sumT[16], sumO[16];
  #pragma unroll
  for (int i = 0; i < 16; ++i){ sumT[i] = 0.f; sumO[i] = 0.f; }

  // pack 16 row labels (<=12, 4 bits each) into 2 uints: saves 14 VGPRs
  unsigned Lpack0 = 0, Lpack1 = 0;
  #pragma unroll
  for (int rf = 0; rf < 4; ++rf)
    #pragma unroll
    for (int e = 0; e < 4; ++e){
      int ri = rf*4 + e;
      unsigned lab = (unsigned)posLab[wr*64 + rf*16 + l4*4 + e];
      if (ri < 8) Lpack0 |= lab << (ri*4);
      else        Lpack1 |= lab << ((ri-8)*4);
    }

  const int nCT = M / 128;
  for (int ct = 0; ct < nCT; ++ct){
    const int colBase = ct*128 + wc*64;
    int labC[4];
    #pragma unroll
    for (int cf = 0; cf < 4; ++cf) labC[cf] = permLabel[colBase + cf*16 + l15];

    f32x4 acc[4][4];
    #pragma unroll
    for (int rf = 0; rf < 4; ++rf)
      #pragma unroll
      for (int cf = 0; cf < 4; ++cf) acc[rf][cf] = (f32x4){0.f,0.f,0.f,0.f};

    #pragma unroll
    for (int kf = 0; kf < 8; ++kf){
      const int k = kf*32 + l4*8;
      bf16x8 b[4];
      #pragma unroll
      for (int cf = 0; cf < 4; ++cf)
        b[cf] = *(const bf16x8*)(spnP + (size_t)(colBase + cf*16 + l15)*DIM + k);
      bf16x8 a[4];
      #pragma unroll
      for (int rf = 0; rf < 4; ++rf)
        a[rf] = *(const bf16x8*)&Ash[swzA(wr*64 + rf*16 + l15, k)];
      #pragma unroll
      for (int rf = 0; rf < 4; ++rf)
        #pragma unroll
        for (int cf = 0; cf < 4; ++cf)
          acc[rf][cf] = __builtin_amdgcn_mfma_f32_16x16x32_bf16(a[rf], b[cf], acc[rf][cf], 0, 0, 0);
    }

    // fused epilogue: exp + class-bucketed per-row partial sums (registers only)
    #pragma unroll
    for (int rf = 0; rf < 4; ++rf)
      #pragma unroll
      for (int cf = 0; cf < 4; ++cf)
        #pragma unroll
        for (int e = 0; e < 4; ++e){
          float ev = __expf(acc[rf][cf][e] * INV_T);
          int ri = rf*4 + e;
          int lr = (int)(((ri < 8 ? Lpack0 : Lpack1) >> ((ri & 7)*4)) & 15u);
          sumT[ri] += ev;
          sumO[ri] += (labC[cf] == lr) ? ev : 0.0f;
        }
  }

  // reduce over the 16 lanes (l15) sharing the same rows
  #pragma unroll
  for (int i = 0; i < 16; ++i){
    #pragma unroll
    for (int o = 1; o < 16; o <<= 1){
      sumT[i] += __shfl_xor(sumT[i], o);
      sumO[i] += __shfl_xor(sumO[i], o);
    }
  }

  // wave owns half the columns of its 64 rows -> stage per-half neg, combine
  if (l15 == 0){
    #pragma unroll
    for (int rf = 0; rf < 4; ++rf)
      #pragma unroll
      for (int e = 0; e < 4; ++e){
        int row = wr*64 + rf*16 + l4*4 + e;
        negH[wc][row] = sumT[rf*4+e] - sumO[rf*4+e];
      }
  }
  __syncthreads();

  if (tid < 64){   // wave 0: two rows per lane
    float part = 0.f;
    #pragma unroll
    for (int h = 0; h < 2; ++h){
      int row = tid*2 + h;
      float pl  = posLogit[row] * INV_T;
      float ep  = __expf(pl);
      float den = ep + negH[0][row] + negH[1][row] + 1e-8f;
      part += __logf(den) - pl;
    }
    #pragma unroll
    for (int o = 1; o < 64; o <<= 1) part += __shfl_xor(part, o);
    if (tid == 0) atomicAdd(accum, (double)part);
  }
}

__global__ void k_final(const double* __restrict__ accum, float* __restrict__ out, int N){
  out[0] = (float)((*accum / (double)N) * 0.07);
}

// ---------------- launch ----------------

extern "C" void kernel_launch(void* const* d_in, const int* in_sizes, int n_in,
                              void* d_out, int out_size, void* d_ws, size_t ws_size,
                              hipStream_t stream){
  const float* sp  = (const float*)d_in[0];
  const float* rp  = (const float*)d_in[1];
  const int*   idx = (const int*)d_in[2];
  const int*   lab = (const int*)d_in[3];
  const int M = in_sizes[0] / DIM;     // 1024
  const int N = in_sizes[2];           // 131072

  char* ws = (char*)d_ws;
  size_t off = 0;
  auto alloc = [&](size_t bytes){ void* p = ws + off; off = (off + bytes + 255) & ~(size_t)255; return p; };
  int*    counts    = (int*)   alloc((size_t)M * NCLS * 4);
  int*    spLabel   = (int*)   alloc((size_t)M * 4);
  int*    newpos    = (int*)   alloc((size_t)M * 4);
  int*    permLabel = (int*)   alloc((size_t)M * 4);
  double* accum     = (double*)alloc(16);
  unsigned short* spnO = (unsigned short*)alloc((size_t)M * DIM * 2);
  unsigned short* spnP = (unsigned short*)alloc((size_t)M * DIM * 2);

  k_zero<<<(M*NCLS + 255)/256, 256, 0, stream>>>(counts, accum, M*NCLS);
  k_hist<<<(N + 255)/256, 256, 0, stream>>>(idx, lab, counts, N);
  k_label_perm<<<1, M, 0, stream>>>(counts, spLabel, newpos, permLabel);
  k_norm_sp<<<M, 64, 0, stream>>>(sp, newpos, spnO, spnP);
  k_main<<<N/128, 256, 0, stream>>>(rp, idx, spnO, spnP, permLabel, spLabel, accum, M);
  k_final<<<1, 1, 0, stream>>>(accum, (float*)d_out, N);
}

// Round 7
// 188.758 us; speedup vs baseline: 1.6499x; 1.6499x over previous
//
#include <hip/hip_runtime.h>

#define NCLS 13
#define DIM  256
#define INV_T (1.0f/0.07f)

typedef short bf16x8 __attribute__((ext_vector_type(8)));
typedef float f32x4  __attribute__((ext_vector_type(4)));

__device__ __forceinline__ float bf2f(unsigned short u){
  union { unsigned u; float f; } v; v.u = ((unsigned)u) << 16; return v.f;
}
__device__ __forceinline__ unsigned short f2bf(float f){
  union { float f; unsigned u; } v; v.f = f;
  unsigned r = v.u + 0x7fffu + ((v.u >> 16) & 1u);
  return (unsigned short)(r >> 16);
}

__device__ __forceinline__ void gload_lds16(const void* g, void* l){
  __builtin_amdgcn_global_load_lds((const __attribute__((address_space(1))) unsigned*)g,
                                   (__attribute__((address_space(3))) unsigned*)l, 16, 0, 0);
}

// ---------------- prep kernels ----------------

__global__ void k_zero(int* counts, unsigned* packLab, double* accum, int n, int np){
  int i = blockIdx.x*blockDim.x + threadIdx.x;
  if (i < n)  counts[i] = 0;
  if (i < np) packLab[i] = 0u;
  if (i == 0) *accum = 0.0;
}

__global__ void k_hist(const int* __restrict__ idx, const int* __restrict__ lab,
                       int* __restrict__ counts, int n){
  int i = blockIdx.x*blockDim.x + threadIdx.x;
  if (i < n) atomicAdd(&counts[idx[i]*NCLS + lab[i]], 1);
}

// one block, M threads (M=1024). argmax labels + label-sorted permutation +
// nibble-packed column labels: packLab[chunk*16 + (pos&15)] nibble ((pos>>4)&7).
__global__ void k_label_perm(const int* __restrict__ counts, int* __restrict__ spLabel,
                             int* __restrict__ newpos, unsigned* __restrict__ packLab){
  int m = threadIdx.x;
  int best = 0; int bc = counts[m*NCLS];
  #pragma unroll
  for (int c = 1; c < NCLS; ++c){ int v = counts[m*NCLS+c]; if (v > bc){ bc = v; best = c; } }
  spLabel[m] = best;

  __shared__ int waveCnt[16][NCLS];
  __shared__ int waveOff[16][NCLS];
  __shared__ int classTot[NCLS];
  __shared__ int classBase[NCLS];
  int lane = m & 63, wid = m >> 6;
  int nw = blockDim.x >> 6;
  int rankInWave = 0;
  unsigned long long below = (1ull << lane) - 1ull;
  for (int c = 0; c < NCLS; ++c){
    unsigned long long bal = __ballot(best == c);
    if (best == c) rankInWave = __popcll(bal & below);
    if (lane == 0) waveCnt[wid][c] = __popcll(bal);
  }
  __syncthreads();
  if (m < NCLS){
    int c = m, s = 0;
    for (int w = 0; w < nw; ++w){ waveOff[w][c] = s; s += waveCnt[w][c]; }
    classTot[c] = s;
  }
  __syncthreads();
  if (m == 0){ int s = 0; for (int c = 0; c < NCLS; ++c){ classBase[c] = s; s += classTot[c]; } }
  __syncthreads();
  int pos = classBase[best] + waveOff[wid][best] + rankInWave;
  newpos[m] = pos;
  atomicOr(&packLab[(pos >> 7)*16 + (pos & 15)], (unsigned)best << (((pos >> 4) & 7)*4));
}

// one wave per superpoint row: normalize, write bf16 in original and permuted order
__global__ void k_norm_sp(const float* __restrict__ sp, const int* __restrict__ newpos,
                          unsigned short* __restrict__ spnO, unsigned short* __restrict__ spnP){
  int m = blockIdx.x, lane = threadIdx.x;
  const float4 v = *(const float4*)(sp + (size_t)m*DIM + lane*4);
  float ss = v.x*v.x + v.y*v.y + v.z*v.z + v.w*v.w;
  #pragma unroll
  for (int o = 1; o < 64; o <<= 1) ss += __shfl_xor(ss, o);
  float rn = 1.0f / sqrtf(ss + 1e-12f);
  uint2 w;
  w.x = (unsigned)f2bf(v.x*rn) | ((unsigned)f2bf(v.y*rn) << 16);
  w.y = (unsigned)f2bf(v.z*rn) | ((unsigned)f2bf(v.w*rn) << 16);
  *(uint2*)(spnO + (size_t)m*DIM + lane*4) = w;
  int p = newpos[m];
  *(uint2*)(spnP + (size_t)p*DIM + lane*4) = w;
}

// ---------------- main fused GEMM ----------------
// 512 threads = 8 waves; wave owns 32 rows x ALL 1024 cols; BM = 256 rows.
// A: in REGISTERS (a[2][8] bf16x8 = 64 VGPR) after one LDS staging pass.
// B: LDS double-buffered 64 KB chunks (128 cols x 256 K), global_load_lds
//    staging with inverse-swizzled source; counted vmcnt + raw s_barrier
//    (never __syncthreads in loop -> chunk c+1 loads stay in flight).
// LDS: 128 KB (B dbuf, reused as A staging) + 2 KB -> 1 block/CU, 2 waves/EU.

#define SBAR()  __builtin_amdgcn_s_barrier()
#define SFENCE() __builtin_amdgcn_sched_barrier(0)

__device__ __forceinline__ void stageB(const unsigned short* __restrict__ spnP,
                                       void* buf, int c, int tid){
  const int wid = tid >> 6;
  #pragma unroll
  for (int i = 0; i < 8; ++i){
    const int d    = i*8192 + tid*16;      // linear dst byte in 64 KB chunk
    const int colp = d >> 9;               // 512 B per column (256 k * 2B)
    const int x    = d & 511;
    const char* src = (const char*)spnP + (size_t)(c*128 + colp)*512 + (x ^ ((colp & 7) << 4));
    char* dst = (char*)buf + i*8192 + wid*1024;   // wave-uniform; HW adds lane*16
    gload_lds16(src, dst);
  }
}

__attribute__((amdgpu_waves_per_eu(1, 2)))
__launch_bounds__(512)
__global__ void k_main(const float* __restrict__ rp, const int* __restrict__ rawIdx,
                       const unsigned short* __restrict__ spnO, const unsigned short* __restrict__ spnP,
                       const unsigned* __restrict__ packLab, const int* __restrict__ spLabel,
                       double* __restrict__ accum, int M){
  __shared__ __align__(16) unsigned short Bsh[2][128*256];  // 128 KB; doubles as A staging
  __shared__ float posLogit[256];
  __shared__ int   posLab[256];

  const int tid  = threadIdx.x;
  const int lane = tid & 63, wid = tid >> 6;
  const int l15  = lane & 15, l4 = lane >> 4;
  const int rowBlock = blockIdx.x * 256;
  char* Ash = (char*)&Bsh[0][0];   // 256 rows x 512 B, XOR-swizzled

  // ---- prologue: wave w owns rows w*32..w*32+31 ----
  for (int rr = 0; rr < 32; ++rr){
    int row = wid*32 + rr;
    const float4 v = *(const float4*)(rp + (size_t)(rowBlock + row)*DIM + lane*4);
    float ss = v.x*v.x + v.y*v.y + v.z*v.z + v.w*v.w;
    #pragma unroll
    for (int o = 1; o < 64; o <<= 1) ss += __shfl_xor(ss, o);
    float rn = 1.0f / sqrtf(ss + 1e-12f);
    uint2 w;
    w.x = (unsigned)f2bf(v.x*rn) | ((unsigned)f2bf(v.y*rn) << 16);
    w.y = (unsigned)f2bf(v.z*rn) | ((unsigned)f2bf(v.w*rn) << 16);
    *(uint2*)(Ash + row*512 + ((lane*8) ^ ((row & 7) << 4))) = w;
    // positive logit using the bf16-rounded values already in regs
    int sidx = rawIdx[rowBlock + row];
    uint2 sv = *(const uint2*)(spnO + (size_t)sidx*DIM + lane*4);
    float d = bf2f(w.x & 0xffff)*bf2f(sv.x & 0xffff)
            + bf2f(w.x >> 16)  *bf2f(sv.x >> 16)
            + bf2f(w.y & 0xffff)*bf2f(sv.y & 0xffff)
            + bf2f(w.y >> 16)  *bf2f(sv.y >> 16);
    #pragma unroll
    for (int o = 1; o < 64; o <<= 1) d += __shfl_xor(d, o);
    if (lane == 0){ posLogit[row] = d; posLab[row] = spLabel[sidx]; }
  }

  // a-frags from own wave's rows (written by this wave; in-order LDS)
  bf16x8 a[2][8];
  #pragma unroll
  for (int rf = 0; rf < 2; ++rf)
    #pragma unroll
    for (int kf = 0; kf < 8; ++kf){
      int row = wid*32 + rf*16 + l15;
      a[rf][kf] = *(const bf16x8*)(Ash + row*512 + ((kf*64 + l4*16) ^ ((row & 7) << 4)));
    }

  __syncthreads();   // all A reads done; A region may now become B buffers

  // row labels packed as nibbles (ri = rf*4+e)
  unsigned Lpack = 0;
  #pragma unroll
  for (int rf = 0; rf < 2; ++rf)
    #pragma unroll
    for (int e = 0; e < 4; ++e)
      Lpack |= ((unsigned)posLab[wid*32 + rf*16 + l4*4 + e]) << ((rf*4 + e)*4);

  float sumT[8], sumO[8];
  #pragma unroll
  for (int i = 0; i < 8; ++i){ sumT[i] = 0.f; sumO[i] = 0.f; }

  stageB(spnP, &Bsh[0][0], 0, tid);   // chunk 0 in flight

  const int nChunks = M / 128;        // 8
  for (int c = 0; c < nChunks; ++c){
    if (c + 1 < nChunks) stageB(spnP, &Bsh[(c+1)&1][0], c+1, tid);
    unsigned cpack = packLab[c*16 + l15];   // column labels for this chunk (8 nibbles)
    if (c + 1 < nChunks) asm volatile("s_waitcnt vmcnt(8)" ::: "memory");
    else                 asm volatile("s_waitcnt vmcnt(0)" ::: "memory");
    SFENCE(); SBAR(); SFENCE();

    const char* Bp = (const char*)&Bsh[c&1][0];
    #pragma unroll
    for (int cf = 0; cf < 8; ++cf){
      const int colp = cf*16 + l15;
      const int swz  = (colp & 7) << 4;
      bf16x8 b[8];
      #pragma unroll
      for (int kf = 0; kf < 8; ++kf)
        b[kf] = *(const bf16x8*)(Bp + colp*512 + ((kf*64 + l4*16) ^ swz));
      f32x4 acc0 = (f32x4){0.f,0.f,0.f,0.f};
      f32x4 acc1 = (f32x4){0.f,0.f,0.f,0.f};
      #pragma unroll
      for (int kf = 0; kf < 8; ++kf){
        acc0 = __builtin_amdgcn_mfma_f32_16x16x32_bf16(a[0][kf], b[kf], acc0, 0, 0, 0);
        acc1 = __builtin_amdgcn_mfma_f32_16x16x32_bf16(a[1][kf], b[kf], acc1, 0, 0, 0);
      }
      const unsigned colLab = (cpack >> (cf*4)) & 15u;
      #pragma unroll
      for (int e = 0; e < 4; ++e){
        float ev0 = __expf(acc0[e] * INV_T);
        float ev1 = __expf(acc1[e] * INV_T);
        sumT[e]   += ev0;
        sumT[4+e] += ev1;
        sumO[e]   += (((Lpack >> (e*4)) & 15u) == colLab) ? ev0 : 0.f;
        sumO[4+e] += (((Lpack >> ((4+e)*4)) & 15u) == colLab) ? ev1 : 0.f;
      }
    }

    SFENCE(); SBAR(); SFENCE();   // all waves done reading buf[c&1]
  }

  // reduce over the 16 l15-lanes sharing each row
  #pragma unroll
  for (int i = 0; i < 8; ++i){
    #pragma unroll
    for (int o = 1; o < 16; o <<= 1){
      sumT[i] += __shfl_xor(sumT[i], o);
      sumO[i] += __shfl_xor(sumO[i], o);
    }
  }

  // wave-local finish: l15==0 lanes (4 per wave) hold 8 rows each
  float part = 0.f;
  if (l15 == 0){
    #pragma unroll
    for (int rf = 0; rf < 2; ++rf)
      #pragma unroll
      for (int e = 0; e < 4; ++e){
        int row = wid*32 + rf*16 + l4*4 + e;
        float pl  = posLogit[row] * INV_T;
        float ep  = __expf(pl);
        float den = ep + (sumT[rf*4+e] - sumO[rf*4+e]) + 1e-8f;
        part += __logf(den) - pl;
      }
  }
  #pragma unroll
  for (int o = 1; o < 64; o <<= 1) part += __shfl_xor(part, o);
  if (lane == 0) atomicAdd(accum, (double)part);
}

__global__ void k_final(const double* __restrict__ accum, float* __restrict__ out, int N){
  out[0] = (float)((*accum / (double)N) * 0.07);
}

// ---------------- launch ----------------

extern "C" void kernel_launch(void* const* d_in, const int* in_sizes, int n_in,
                              void* d_out, int out_size, void* d_ws, size_t ws_size,
                              hipStream_t stream){
  const float* sp  = (const float*)d_in[0];
  const float* rp  = (const float*)d_in[1];
  const int*   idx = (const int*)d_in[2];
  const int*   lab = (const int*)d_in[3];
  const int M = in_sizes[0] / DIM;     // 1024
  const int N = in_sizes[2];           // 131072

  char* ws = (char*)d_ws;
  size_t off = 0;
  auto alloc = [&](size_t bytes){ void* p = ws + off; off = (off + bytes + 255) & ~(size_t)255; return p; };
  int*      counts  = (int*)     alloc((size_t)M * NCLS * 4);
  int*      spLabel = (int*)     alloc((size_t)M * 4);
  int*      newpos  = (int*)     alloc((size_t)M * 4);
  unsigned* packLab = (unsigned*)alloc((size_t)(M/128) * 16 * 4);
  double*   accum   = (double*)  alloc(16);
  unsigned short* spnO = (unsigned short*)alloc((size_t)M * DIM * 2);
  unsigned short* spnP = (unsigned short*)alloc((size_t)M * DIM * 2);

  k_zero<<<(M*NCLS + 255)/256, 256, 0, stream>>>(counts, packLab, accum, M*NCLS, (M/128)*16);
  k_hist<<<(N + 255)/256, 256, 0, stream>>>(idx, lab, counts, N);
  k_label_perm<<<1, M, 0, stream>>>(counts, spLabel, newpos, packLab);
  k_norm_sp<<<M, 64, 0, stream>>>(sp, newpos, spnO, spnP);
  k_main<<<N/256, 512, 0, stream>>>(rp, idx, spnO, spnP, packLab, spLabel, accum, M);
  k_final<<<1, 1, 0, stream>>>(accum, (float*)d_out, N);
}